// Round 5
// baseline (218.991 us; speedup 1.0000x reference)
//
#include <hip/hip_runtime.h>
#include <math.h>

// PedestrianDetector: features[B,T,2048] fp32 -> bbox head (D->12), conf head (D->3),
// sigmoid, stable top-3 sort, threshold 0.5, packed outputs:
//   out[0 .. 12N)    boxes [N,3,4] (zeroed where invalid)
//   out[12N .. 15N)  conf  [N,3]   (sorted desc)
//   out[15N .. 18N)  valid [N,3]   (1.0/0.0)
// N = B*T = 16384. Memory-bound: 134 MB feature stream; floor ~21 us at 6.3 TB/s.
//
// v5: coalesced global loads (v4 had 64-line-per-instr scattered loads) + v4's
// scalar-path W. 256 blocks x 1024 threads (16 waves), 64 rows/block, 32 tiles x 64 d.
// Staging: 1 float4/thread/tile, XOR-swizzled into LDS (chunk ^ (row&15)) ->
// aligned b128 reads/writes, exactly 2-way bank aliasing (free, m136). Wave w
// computes d-slice [tile*64 + 4w, +4) for all 64 rows (lane=row); W operand is
// wave-uniform -> s_load -> v_fmac with SGPR src (zero W vector-memory ops).
// Distance-2 register prefetch covers HBM latency at the commit. One barrier/tile.
// End: log2 cross-wave fold via 8-slot LDS buffer (self-consumed slots, race-free),
// wave 0 does sigmoid + stable top-3 + threshold + stores from registers.

#define DCOLS 2048
#define RPB   64                  // rows per block
#define TD    64                  // d per tile
#define NTILE (DCOLS / TD)        // 32

__global__ __launch_bounds__(1024, 4)
void ped_det_kernel(const float* __restrict__ feat,
                    const float* __restrict__ Wb,   // [2048][12]
                    const float* __restrict__ bb,   // [12]
                    const float* __restrict__ Wc,   // [2048][3]
                    const float* __restrict__ bc,   // [3]
                    float* __restrict__ out,
                    int nrows)
{
    __shared__ float4 buf[2][RPB * 16];   // 32,768 B: [row][16 chunks], XOR-swizzled
    __shared__ float  P[8 * RPB * 15];    // 30,720 B: fold slots

    const int t    = threadIdx.x;
    const int lane = t & 63;
    const int w    = t >> 6;                              // wave 0..15
    const int wu   = __builtin_amdgcn_readfirstlane(w);   // force wave-uniform
    const size_t row0 = (size_t)blockIdx.x * RPB;

    // staging coords: thread t stages row sr, 16-float4 chunk sc of each tile
    const int sr = t >> 4;                 // 0..63
    const int sc = t & 15;                 // 0..15
    const int sp = sc ^ (sr & 15);         // phys chunk (XOR swizzle)
    const float* gsrc = feat + (row0 + sr) * DCOLS + sc * 4;

    // compute-side read slot: lane=row, chunk = wu
    const int rslot = lane * 16 + (wu ^ (lane & 15));

    float acc[15];
#pragma unroll
    for (int j = 0; j < 15; ++j) acc[j] = 0.0f;

    // ---- prologue: tile 0 -> LDS, tile 1 -> reg
    {
        const float4 r0 = *(const float4*)(gsrc);
        buf[0][sr * 16 + sp] = r0;
    }
    float4 reg1 = *(const float4*)(gsrc + TD);

    for (int tt = 0; tt < NTILE; ++tt) {
        __syncthreads();   // commits of tile tt visible; computes of tt-1 done

        // distance-2 prefetch
        float4 reg2;
        if (tt + 2 < NTILE) reg2 = *(const float4*)(gsrc + (size_t)(tt + 2) * TD);

        // ---- compute: 4 d x 15 outputs, W via scalar path
        const float4 f = buf[tt & 1][rslot];
        const float fv[4] = { f.x, f.y, f.z, f.w };
        const int du = tt * TD + wu * 4;                        // wave-uniform d base
        const float* __restrict__ wbp = Wb + (size_t)du * 12;   // 48 floats
        const float* __restrict__ wcp = Wc + (size_t)du * 3;    // 12 floats
#pragma unroll
        for (int j = 0; j < 4; ++j) {
            const float v = fv[j];
            acc[0]  += v * wbp[j * 12 + 0];
            acc[1]  += v * wbp[j * 12 + 1];
            acc[2]  += v * wbp[j * 12 + 2];
            acc[3]  += v * wbp[j * 12 + 3];
            acc[4]  += v * wbp[j * 12 + 4];
            acc[5]  += v * wbp[j * 12 + 5];
            acc[6]  += v * wbp[j * 12 + 6];
            acc[7]  += v * wbp[j * 12 + 7];
            acc[8]  += v * wbp[j * 12 + 8];
            acc[9]  += v * wbp[j * 12 + 9];
            acc[10] += v * wbp[j * 12 + 10];
            acc[11] += v * wbp[j * 12 + 11];
            acc[12] += v * wcp[j * 3 + 0];
            acc[13] += v * wcp[j * 3 + 1];
            acc[14] += v * wcp[j * 3 + 2];
        }

        // ---- commit tile tt+1 (loaded LAST iter -> latency fully covered)
        if (tt + 1 < NTILE) buf[(tt + 1) & 1][sr * 16 + sp] = reg1;
        reg1 = reg2;
    }

    // ---- cross-wave fold: 16 -> 1 partials per row, log2 rounds.
    // Each round's writers target slots last read by THEMSELVES (race-free).
    // Round A: waves 8..15 -> slots 0..7; waves 0..7 add slot w.
    if (w >= 8) {
        float* pp = &P[((w - 8) * RPB + lane) * 15];
#pragma unroll
        for (int j = 0; j < 15; ++j) pp[j] = acc[j];
    }
    __syncthreads();
    if (w < 8) {
        const float* pp = &P[(w * RPB + lane) * 15];
#pragma unroll
        for (int j = 0; j < 15; ++j) acc[j] += pp[j];
    }
    // Round B: waves 4..7 -> own slot w; waves 0..3 add slot w+4.
    if (w >= 4 && w < 8) {
        float* pp = &P[(w * RPB + lane) * 15];
#pragma unroll
        for (int j = 0; j < 15; ++j) pp[j] = acc[j];
    }
    __syncthreads();
    if (w < 4) {
        const float* pp = &P[((w + 4) * RPB + lane) * 15];
#pragma unroll
        for (int j = 0; j < 15; ++j) acc[j] += pp[j];
    }
    // Round C: waves 2..3 -> own slot; waves 0..1 add slot w+2.
    if (w >= 2 && w < 4) {
        float* pp = &P[(w * RPB + lane) * 15];
#pragma unroll
        for (int j = 0; j < 15; ++j) pp[j] = acc[j];
    }
    __syncthreads();
    if (w < 2) {
        const float* pp = &P[((w + 2) * RPB + lane) * 15];
#pragma unroll
        for (int j = 0; j < 15; ++j) acc[j] += pp[j];
    }
    // Round D: wave 1 -> slot 1; wave 0 adds slot 1.
    if (w == 1) {
        float* pp = &P[(1 * RPB + lane) * 15];
#pragma unroll
        for (int j = 0; j < 15; ++j) pp[j] = acc[j];
    }
    __syncthreads();

    // ---- epilogue: wave 0 holds full sums for its 64 rows
    if (w == 0) {
        const float* pp = &P[(1 * RPB + lane) * 15];
        float s[15];
#pragma unroll
        for (int j = 0; j < 15; ++j) s[j] = acc[j] + pp[j];

        float box[12];
#pragma unroll
        for (int j = 0; j < 12; ++j) box[j] = s[j] + bb[j];
        float conf[3];
#pragma unroll
        for (int a = 0; a < 3; ++a)
            conf[a] = 1.0f / (1.0f + __expf(-(s[12 + a] + bc[a])));

        // stable descending top-3 (ties -> lower index), matches lax.top_k
        int i0 = 0; float m0 = conf[0];
        if (conf[1] > m0) { i0 = 1; m0 = conf[1]; }
        if (conf[2] > m0) { i0 = 2; m0 = conf[2]; }
        const int ra = (i0 == 0) ? 1 : 0;
        const int rb = (i0 == 2) ? 1 : 2;
        int i1, i2;
        if (conf[rb] > conf[ra]) { i1 = rb; i2 = ra; }
        else                     { i1 = ra; i2 = rb; }
        const int idx[3] = { i0, i1, i2 };

        const int ro = (int)row0 + lane;
        float* boxout  = out + (size_t)ro * 12;
        float* confout = out + (size_t)nrows * 12 + (size_t)ro * 3;
        float* valout  = out + (size_t)nrows * 15 + (size_t)ro * 3;
#pragma unroll
        for (int sl = 0; sl < 3; ++sl) {
            const int   a   = idx[sl];
            const float cv  = conf[a];
            const bool  vld = cv > 0.5f;
            float4 bx;
            bx.x = vld ? box[a * 4 + 0] : 0.0f;
            bx.y = vld ? box[a * 4 + 1] : 0.0f;
            bx.z = vld ? box[a * 4 + 2] : 0.0f;
            bx.w = vld ? box[a * 4 + 3] : 0.0f;
            *(float4*)(boxout + sl * 4) = bx;
            confout[sl] = cv;
            valout[sl]  = vld ? 1.0f : 0.0f;
        }
    }
}

extern "C" void kernel_launch(void* const* d_in, const int* in_sizes, int n_in,
                              void* d_out, int out_size, void* d_ws, size_t ws_size,
                              hipStream_t stream) {
    const float* feat = (const float*)d_in[0];
    const float* Wb   = (const float*)d_in[1];
    const float* bb   = (const float*)d_in[2];
    const float* Wc   = (const float*)d_in[3];
    const float* bc   = (const float*)d_in[4];
    float* out = (float*)d_out;

    const int nrows   = in_sizes[0] / DCOLS;   // 16384
    const int nblocks = nrows / RPB;           // 256 -> 1 block/CU

    ped_det_kernel<<<dim3(nblocks), dim3(1024), 0, stream>>>(
        feat, Wb, bb, Wc, bc, out, nrows);
}